// Round 4
// baseline (698.581 us; speedup 1.0000x reference)
//
#include <hip/hip_runtime.h>
#include <hip/hip_bf16.h>

#define LEAKY 0.2f

using h2_t = __attribute__((ext_vector_type(2))) _Float16;
using h4_t = __attribute__((ext_vector_type(4))) _Float16;

// ---------------- CSR build ----------------

__global__ __launch_bounds__(256) void count_kernel(const int* __restrict__ ei,
                                                    int* __restrict__ cnt,
                                                    int E, int ET) {
    int e = blockIdx.x * 256 + threadIdx.x;
    if (e >= ET) return;
    int d = (e < E) ? ei[E + e] : (e - E);
    atomicAdd(&cnt[d], 1);
}

__global__ __launch_bounds__(1024) void scan_kernel(const int* __restrict__ cnt,
                                                    int* __restrict__ rowptr, int N) {
    __shared__ int sums[1024];
    int tid = threadIdx.x;
    int chunk = (N + 1023) >> 10;
    int begin = tid * chunk;
    int end = min(begin + chunk, N);
    int s = 0;
    for (int i = begin; i < end; i++) s += cnt[i];
    sums[tid] = s;
    __syncthreads();
    for (int off = 1; off < 1024; off <<= 1) {
        int v = 0;
        if (tid >= off) v = sums[tid - off];
        __syncthreads();
        sums[tid] += v;
        __syncthreads();
    }
    int base = (tid == 0) ? 0 : sums[tid - 1];
    for (int i = begin; i < end; i++) { rowptr[i] = base; base += cnt[i]; }
    if (tid == 0) rowptr[N] = sums[1023];
}

__global__ __launch_bounds__(256) void scatter_kernel(const int* __restrict__ ei,
                                                      const int* __restrict__ rowptr,
                                                      int* __restrict__ cursor,
                                                      int* __restrict__ perm,
                                                      int E, int ET) {
    int e = blockIdx.x * 256 + threadIdx.x;
    if (e >= ET) return;
    int s, d;
    if (e < E) { s = ei[e]; d = ei[E + e]; } else { s = e - E; d = s; }
    int pos = atomicAdd(&cursor[d], 1);
    perm[rowptr[d] + pos] = s;  // store src node id directly
}

// ---------------- GEMM + fused scores ----------------
// Hh[M,HC] = fp16(X[M,128] @ W[128,HC]); es/ed[n,h] = dot(h[n,h,:], a_s/a_d[h,:])
// Block tile 128x64, BK=32, 256 threads, 8x4 micro-tile. Each thread's 4-col
// group lies inside one head (C is a multiple of 4).
// C=16: 64-col block = 4 whole heads -> shfl-reduce over 4 lanes, plain store.
// C=40: heads straddle blocks -> pair-merge via shfl_xor(1) + atomicAdd.

#define XS_LD 132

template <int C>
__global__ __launch_bounds__(256) void gemm_kernel(const float* __restrict__ X,
                                                   const float* __restrict__ W,
                                                   const float* __restrict__ As,
                                                   const float* __restrict__ Ad,
                                                   _Float16* __restrict__ Hh,
                                                   float* __restrict__ es,
                                                   float* __restrict__ ed,
                                                   int M) {
    constexpr int K = 128;
    constexpr int HC = 8 * C;
    __shared__ float Xs[32 * XS_LD];
    __shared__ float Ws[32 * 64];

    int tid = threadIdx.x;
    int tx = tid & 15;
    int ty = tid >> 4;
    int m0 = blockIdx.x * 128;
    int n0 = blockIdx.y * 64;

    float acc[8][4];
#pragma unroll
    for (int r = 0; r < 8; r++)
#pragma unroll
        for (int c = 0; c < 4; c++) acc[r][c] = 0.f;

    int lx_m = tid >> 3;
    int lx_kq = tid & 7;
    int lw_k = tid >> 4;
    int lw_nq = tid & 15;

    for (int k0 = 0; k0 < K; k0 += 32) {
#pragma unroll
        for (int p = 0; p < 4; p++) {
            int mi = p * 32 + lx_m;
            int row = m0 + mi;
            float4 v = make_float4(0.f, 0.f, 0.f, 0.f);
            if (row < M)
                v = *(const float4*)&X[(size_t)row * K + k0 + 4 * lx_kq];
            Xs[(4 * lx_kq + 0) * XS_LD + mi] = v.x;
            Xs[(4 * lx_kq + 1) * XS_LD + mi] = v.y;
            Xs[(4 * lx_kq + 2) * XS_LD + mi] = v.z;
            Xs[(4 * lx_kq + 3) * XS_LD + mi] = v.w;
        }
#pragma unroll
        for (int p = 0; p < 2; p++) {
            int kr = p * 16 + lw_k;
            float4 v = *(const float4*)&W[(size_t)(k0 + kr) * HC + n0 + 4 * lw_nq];
            *(float4*)&Ws[kr * 64 + 4 * lw_nq] = v;
        }
        __syncthreads();

#pragma unroll 8
        for (int kk = 0; kk < 32; kk++) {
            float4 a0 = *(float4*)&Xs[kk * XS_LD + ty * 8];
            float4 a1 = *(float4*)&Xs[kk * XS_LD + ty * 8 + 4];
            float4 bv = *(float4*)&Ws[kk * 64 + tx * 4];
            float av[8] = {a0.x, a0.y, a0.z, a0.w, a1.x, a1.y, a1.z, a1.w};
            float bw[4] = {bv.x, bv.y, bv.z, bv.w};
#pragma unroll
            for (int r = 0; r < 8; r++)
#pragma unroll
                for (int c = 0; c < 4; c++)
                    acc[r][c] = fmaf(av[r], bw[c], acc[r][c]);
        }
        __syncthreads();
    }

    int gcol0 = n0 + tx * 4;
    int h = gcol0 / C;  // head of this thread's 4-col group
    float4 av = *(const float4*)&As[gcol0];
    float4 dv = *(const float4*)&Ad[gcol0];

#pragma unroll
    for (int r = 0; r < 8; r++) {
        int row = m0 + ty * 8 + r;
        bool ok = row < M;
        if (ok) {
            h4_t hv = {(_Float16)acc[r][0], (_Float16)acc[r][1],
                       (_Float16)acc[r][2], (_Float16)acc[r][3]};
            *(h4_t*)&Hh[(size_t)row * HC + gcol0] = hv;
        }
        float ps = acc[r][0] * av.x + acc[r][1] * av.y + acc[r][2] * av.z + acc[r][3] * av.w;
        float pd = acc[r][0] * dv.x + acc[r][1] * dv.y + acc[r][2] * dv.z + acc[r][3] * dv.w;
        if constexpr (C == 16) {
            ps += __shfl_xor(ps, 1); pd += __shfl_xor(pd, 1);
            ps += __shfl_xor(ps, 2); pd += __shfl_xor(pd, 2);
            if ((tx & 3) == 0 && ok) {
                es[row * 8 + h] = ps;
                ed[row * 8 + h] = pd;
            }
        } else {
            // head boundaries (multiples of 10 in 4-col units) are even in tx,
            // so lane pairs (2k,2k+1) always share a head -> merge then atomic.
            ps += __shfl_xor(ps, 1); pd += __shfl_xor(pd, 1);
            if ((tx & 1) == 0 && ok) {
                atomicAdd(&es[row * 8 + h], ps);
                atomicAdd(&ed[row * 8 + h], pd);
            }
        }
    }
}

// ---------------- wave-per-dst softmax + aggregation (fp16 gather) ----------------
// Phase 1 (max) uses 8-edge x 8-head lane layout (head = lane&7, eslot = lane>>3).
// Fused phase 2+3: per 8-edge chunk compute unnormalized alpha once per
// (edge,head), broadcast src via readlane (SGPR addressing) and alpha via shfl,
// gather fp16 features, fp32 accumulate; normalize by denom at the end.
// Feature lane layout: C=16 (HC=128): h2_t at 2*lane (one head per lane pair-slice).
//                      C=40 (HC=320): h4_t at 4*lane + scalar at 256+lane.

template <int C, bool FINAL>
__global__ __launch_bounds__(256) void agg_kernel(const _Float16* __restrict__ Hf,
                                                  const float* __restrict__ es,
                                                  const float* __restrict__ ed,
                                                  const int* __restrict__ rowptr,
                                                  const int* __restrict__ perm,
                                                  const float* __restrict__ bias,
                                                  float* __restrict__ Out, int N) {
    constexpr int HC = 8 * C;
    __shared__ float sfeat[FINAL ? 4 : 1][FINAL ? HC : 1];
    int lane = threadIdx.x & 63;
    int wid = threadIdx.x >> 6;
    int d = blockIdx.x * 4 + wid;
    bool active = d < N;
    int start = 0, end = 0;
    if (active) { start = rowptr[d]; end = rowptr[d + 1]; }
    start = __builtin_amdgcn_readfirstlane(start);
    end = __builtin_amdgcn_readfirstlane(end);
    int h8 = lane & 7;
    int eslot = lane >> 3;
    float edh = active ? ed[d * 8 + h8] : 0.f;

    // ---- phase 1: per-head max over edges ----
    float mx = -3.0e38f;
    for (int q = start + eslot; q < end; q += 8) {
        int s = perm[q];
        float v = es[s * 8 + h8] + edh;
        v = (v >= 0.f) ? v : LEAKY * v;
        mx = fmaxf(mx, v);
    }
#pragma unroll
    for (int m = 8; m < 64; m <<= 1) mx = fmaxf(mx, __shfl_xor(mx, m));

    // head indices for this lane's feature elements
    int hh03 = FINAL ? (4 * lane) / C : (2 * lane) / C;  // C=16: == eslot
    int hh4 = FINAL ? (256 + lane) / C : 0;

    float acc[FINAL ? 5 : 2];
#pragma unroll
    for (int p = 0; p < (FINAL ? 5 : 2); p++) acc[p] = 0.f;

    // ---- fused phase 2+3 ----
    float dsum = 0.f;
    for (int q0 = start; q0 < end; q0 += 8) {
        int qq = q0 + eslot;
        int s_l = 0;
        float a_l = 0.f;
        if (qq < end) {
            s_l = perm[qq];
            float v = es[s_l * 8 + h8] + edh;
            v = (v >= 0.f) ? v : LEAKY * v;
            a_l = __expf(v - mx);
        }
        dsum += a_l;
#pragma unroll
        for (int e = 0; e < 8; e++) {
            if (q0 + e < end) {
                int s = __builtin_amdgcn_readlane(s_l, e * 8);
                const _Float16* hp = Hf + (size_t)s * HC;
                if constexpr (!FINAL) {
                    h2_t hv = *(const h2_t*)&hp[2 * lane];
                    float a0 = __shfl(a_l, e * 8 + hh03);
                    acc[0] = fmaf(a0, (float)hv[0], acc[0]);
                    acc[1] = fmaf(a0, (float)hv[1], acc[1]);
                } else {
                    h4_t hv = *(const h4_t*)&hp[4 * lane];
                    float hx = (float)hp[256 + lane];
                    float a03 = __shfl(a_l, e * 8 + hh03);
                    float a4 = __shfl(a_l, e * 8 + hh4);
                    acc[0] = fmaf(a03, (float)hv[0], acc[0]);
                    acc[1] = fmaf(a03, (float)hv[1], acc[1]);
                    acc[2] = fmaf(a03, (float)hv[2], acc[2]);
                    acc[3] = fmaf(a03, (float)hv[3], acc[3]);
                    acc[4] = fmaf(a4, hx, acc[4]);
                }
            }
        }
    }

    // ---- normalize ----
#pragma unroll
    for (int m = 8; m < 64; m <<= 1) dsum += __shfl_xor(dsum, m);
    float rden = 1.0f / (dsum + 1e-16f);

    if constexpr (!FINAL) {
        float r0 = __shfl(rden, hh03);
        acc[0] *= r0;
        acc[1] *= r0;
        if (active) {
            float2 bv = *(const float2*)&bias[2 * lane];
            float vx = acc[0] + bv.x;
            float vy = acc[1] + bv.y;
            vx = (vx > 0.f) ? vx : expm1f(vx);  // ELU
            vy = (vy > 0.f) ? vy : expm1f(vy);
            float* op = Out + (size_t)d * HC;
            *(float2*)&op[2 * lane] = make_float2(vx, vy);
        }
    } else {
        float r03 = __shfl(rden, hh03);
        float r4 = __shfl(rden, hh4);
#pragma unroll
        for (int j = 0; j < 4; j++) sfeat[wid][4 * lane + j] = acc[j] * r03;
        sfeat[wid][256 + lane] = acc[4] * r4;
        __syncthreads();
        if (active && lane < C) {
            float s = 0.f;
#pragma unroll
            for (int h = 0; h < 8; h++) s += sfeat[wid][h * C + lane];
            Out[(size_t)d * C + lane] = s * 0.125f + bias[lane];
        }
    }
}

// ---------------- launch ----------------

extern "C" void kernel_launch(void* const* d_in, const int* in_sizes, int n_in,
                              void* d_out, int out_size, void* d_ws, size_t ws_size,
                              hipStream_t stream) {
    const float* x   = (const float*)d_in[0];
    const int*   ei  = (const int*)d_in[1];
    const float* W1  = (const float*)d_in[2];
    const float* a1s = (const float*)d_in[3];
    const float* a1d = (const float*)d_in[4];
    const float* b1  = (const float*)d_in[5];
    const float* W2  = (const float*)d_in[6];
    const float* a2s = (const float*)d_in[7];
    const float* a2d = (const float*)d_in[8];
    const float* b2  = (const float*)d_in[9];
    const float* W3  = (const float*)d_in[10];
    const float* a3s = (const float*)d_in[11];
    const float* a3d = (const float*)d_in[12];
    const float* b3  = (const float*)d_in[13];
    float* out = (float*)d_out;

    const int N = in_sizes[0] / 128;
    const int E = in_sizes[1] / 2;
    const int ET = E + N;

    char* p = (char*)d_ws;
    _Float16* hbuf = (_Float16*)p; p += (size_t)N * 320 * 2;
    float* xbuf  = (float*)p; p += (size_t)N * 128 * 4;
    float* es    = (float*)p; p += (size_t)N * 8 * 4;
    float* edd   = (float*)p; p += (size_t)N * 8 * 4;
    int* cnt     = (int*)p;   p += (size_t)N * 4;
    int* rowptr  = (int*)p;   p += (size_t)(N + 1) * 4;
    int* perm    = (int*)p;   p += (size_t)ET * 4;

    // CSR build (shared by all 3 layers)
    hipMemsetAsync(cnt, 0, (size_t)N * 4, stream);
    count_kernel<<<(ET + 255) / 256, 256, 0, stream>>>(ei, cnt, E, ET);
    scan_kernel<<<1, 1024, 0, stream>>>(cnt, rowptr, N);
    hipMemsetAsync(cnt, 0, (size_t)N * 4, stream);
    scatter_kernel<<<(ET + 255) / 256, 256, 0, stream>>>(ei, rowptr, cnt, perm, E, ET);

    int agg_grid = (N + 3) / 4;
    dim3 g128((N + 127) / 128, 2);   // HC=128
    dim3 g320((N + 127) / 128, 5);   // HC=320

    // layer 1: GAT(128 -> 8x16, concat) + ELU
    gemm_kernel<16><<<g128, 256, 0, stream>>>(x, W1, a1s, a1d, hbuf, es, edd, N);
    agg_kernel<16, false><<<agg_grid, 256, 0, stream>>>(hbuf, es, edd, rowptr, perm, b1, xbuf, N);

    // layer 2: GAT(128 -> 8x16, concat) + ELU
    gemm_kernel<16><<<g128, 256, 0, stream>>>(xbuf, W2, a2s, a2d, hbuf, es, edd, N);
    agg_kernel<16, false><<<agg_grid, 256, 0, stream>>>(hbuf, es, edd, rowptr, perm, b2, xbuf, N);

    // layer 3: GAT(128 -> 8x40, mean over heads); atomics need zeroed es/ed
    hipMemsetAsync(es, 0, (size_t)N * 8 * 4, stream);
    hipMemsetAsync(edd, 0, (size_t)N * 8 * 4, stream);
    gemm_kernel<40><<<g320, 256, 0, stream>>>(xbuf, W3, a3s, a3d, hbuf, es, edd, N);
    agg_kernel<40, true><<<agg_grid, 256, 0, stream>>>(hbuf, es, edd, rowptr, perm, b3, out, N);
}

// Round 5
// 567.677 us; speedup vs baseline: 1.2306x; 1.2306x over previous
//
#include <hip/hip_runtime.h>
#include <hip/hip_bf16.h>

#define LEAKY 0.2f

using h2_t = __attribute__((ext_vector_type(2))) _Float16;
using h4_t = __attribute__((ext_vector_type(4))) _Float16;

// ---------------- CSR build ----------------

__global__ __launch_bounds__(256) void count_kernel(const int* __restrict__ ei,
                                                    int* __restrict__ cnt,
                                                    int E, int ET) {
    int e = blockIdx.x * 256 + threadIdx.x;
    if (e >= ET) return;
    int d = (e < E) ? ei[E + e] : (e - E);
    atomicAdd(&cnt[d], 1);
}

__global__ __launch_bounds__(1024) void scan_kernel(const int* __restrict__ cnt,
                                                    int* __restrict__ rowptr, int N) {
    __shared__ int sums[1024];
    int tid = threadIdx.x;
    int chunk = (N + 1023) >> 10;
    int begin = tid * chunk;
    int end = min(begin + chunk, N);
    int s = 0;
    for (int i = begin; i < end; i++) s += cnt[i];
    sums[tid] = s;
    __syncthreads();
    for (int off = 1; off < 1024; off <<= 1) {
        int v = 0;
        if (tid >= off) v = sums[tid - off];
        __syncthreads();
        sums[tid] += v;
        __syncthreads();
    }
    int base = (tid == 0) ? 0 : sums[tid - 1];
    for (int i = begin; i < end; i++) { rowptr[i] = base; base += cnt[i]; }
    if (tid == 0) rowptr[N] = sums[1023];
}

__global__ __launch_bounds__(256) void scatter_kernel(const int* __restrict__ ei,
                                                      const int* __restrict__ rowptr,
                                                      int* __restrict__ cursor,
                                                      int* __restrict__ perm,
                                                      int E, int ET) {
    int e = blockIdx.x * 256 + threadIdx.x;
    if (e >= ET) return;
    int s, d;
    if (e < E) { s = ei[e]; d = ei[E + e]; } else { s = e - E; d = s; }
    int pos = atomicAdd(&cursor[d], 1);
    perm[rowptr[d] + pos] = s;  // store src node id directly
}

// ---------------- GEMM (+ fused scores only for C=16, atomic-free) ----------------
// Hh[M,HC] = fp16(X[M,128] @ W[128,HC]).
// FUSE=true (C=16): 64-col block = 4 whole heads -> shfl-reduce over 4 lanes,
// plain store of es/ed. No atomics anywhere.

#define XS_LD 132

template <int C, bool FUSE>
__global__ __launch_bounds__(256) void gemm_kernel(const float* __restrict__ X,
                                                   const float* __restrict__ W,
                                                   const float* __restrict__ As,
                                                   const float* __restrict__ Ad,
                                                   _Float16* __restrict__ Hh,
                                                   float* __restrict__ es,
                                                   float* __restrict__ ed,
                                                   int M) {
    constexpr int K = 128;
    constexpr int HC = 8 * C;
    __shared__ float Xs[32 * XS_LD];
    __shared__ float Ws[32 * 64];

    int tid = threadIdx.x;
    int tx = tid & 15;
    int ty = tid >> 4;
    int m0 = blockIdx.x * 128;
    int n0 = blockIdx.y * 64;

    float acc[8][4];
#pragma unroll
    for (int r = 0; r < 8; r++)
#pragma unroll
        for (int c = 0; c < 4; c++) acc[r][c] = 0.f;

    int lx_m = tid >> 3;
    int lx_kq = tid & 7;
    int lw_k = tid >> 4;
    int lw_nq = tid & 15;

    for (int k0 = 0; k0 < K; k0 += 32) {
#pragma unroll
        for (int p = 0; p < 4; p++) {
            int mi = p * 32 + lx_m;
            int row = m0 + mi;
            float4 v = make_float4(0.f, 0.f, 0.f, 0.f);
            if (row < M)
                v = *(const float4*)&X[(size_t)row * K + k0 + 4 * lx_kq];
            Xs[(4 * lx_kq + 0) * XS_LD + mi] = v.x;
            Xs[(4 * lx_kq + 1) * XS_LD + mi] = v.y;
            Xs[(4 * lx_kq + 2) * XS_LD + mi] = v.z;
            Xs[(4 * lx_kq + 3) * XS_LD + mi] = v.w;
        }
#pragma unroll
        for (int p = 0; p < 2; p++) {
            int kr = p * 16 + lw_k;
            float4 v = *(const float4*)&W[(size_t)(k0 + kr) * HC + n0 + 4 * lw_nq];
            *(float4*)&Ws[kr * 64 + 4 * lw_nq] = v;
        }
        __syncthreads();

#pragma unroll 8
        for (int kk = 0; kk < 32; kk++) {
            float4 a0 = *(float4*)&Xs[kk * XS_LD + ty * 8];
            float4 a1 = *(float4*)&Xs[kk * XS_LD + ty * 8 + 4];
            float4 bv = *(float4*)&Ws[kk * 64 + tx * 4];
            float av[8] = {a0.x, a0.y, a0.z, a0.w, a1.x, a1.y, a1.z, a1.w};
            float bw[4] = {bv.x, bv.y, bv.z, bv.w};
#pragma unroll
            for (int r = 0; r < 8; r++)
#pragma unroll
                for (int c = 0; c < 4; c++)
                    acc[r][c] = fmaf(av[r], bw[c], acc[r][c]);
        }
        __syncthreads();
    }

    int gcol0 = n0 + tx * 4;

#pragma unroll
    for (int r = 0; r < 8; r++) {
        int row = m0 + ty * 8 + r;
        bool ok = row < M;
        if (ok) {
            h4_t hv = {(_Float16)acc[r][0], (_Float16)acc[r][1],
                       (_Float16)acc[r][2], (_Float16)acc[r][3]};
            *(h4_t*)&Hh[(size_t)row * HC + gcol0] = hv;
        }
        if constexpr (FUSE) {
            int h = gcol0 / C;
            float4 av = *(const float4*)&As[gcol0];
            float4 dv = *(const float4*)&Ad[gcol0];
            float ps = acc[r][0] * av.x + acc[r][1] * av.y + acc[r][2] * av.z + acc[r][3] * av.w;
            float pd = acc[r][0] * dv.x + acc[r][1] * dv.y + acc[r][2] * dv.z + acc[r][3] * dv.w;
            ps += __shfl_xor(ps, 1); pd += __shfl_xor(pd, 1);
            ps += __shfl_xor(ps, 2); pd += __shfl_xor(pd, 2);
            if ((tx & 3) == 0 && ok) {
                es[row * 8 + h] = ps;
                ed[row * 8 + h] = pd;
            }
        }
    }
}

// ---------------- per-node attention scores (fp16 features) ----------------

template <int C>
__global__ __launch_bounds__(256) void attn_score_kernel(const _Float16* __restrict__ Hf,
                                                         const float* __restrict__ as_,
                                                         const float* __restrict__ ad_,
                                                         float* __restrict__ es,
                                                         float* __restrict__ ed, int N) {
    int i = blockIdx.x * 256 + threadIdx.x;
    if (i >= N * 8) return;
    int n = i >> 3, h = i & 7;
    const _Float16* hp = Hf + (size_t)n * 8 * C + h * C;
    const float* ap = as_ + h * C;
    const float* bp = ad_ + h * C;
    float s = 0.f, d = 0.f;
#pragma unroll
    for (int c = 0; c < C / 2; c++) {
        h2_t v = *(const h2_t*)&hp[2 * c];
        float v0 = (float)v[0], v1 = (float)v[1];
        s = fmaf(v0, ap[2 * c], s);
        d = fmaf(v0, bp[2 * c], d);
        s = fmaf(v1, ap[2 * c + 1], s);
        d = fmaf(v1, bp[2 * c + 1], d);
    }
    es[i] = s;
    ed[i] = d;
}

// ---------------- wave-per-dst softmax + aggregation (fp16 gather) ----------------

template <int C, bool FINAL>
__global__ __launch_bounds__(256) void agg_kernel(const _Float16* __restrict__ Hf,
                                                  const float* __restrict__ es,
                                                  const float* __restrict__ ed,
                                                  const int* __restrict__ rowptr,
                                                  const int* __restrict__ perm,
                                                  const float* __restrict__ bias,
                                                  float* __restrict__ Out, int N) {
    constexpr int HC = 8 * C;
    __shared__ float sfeat[FINAL ? 4 : 1][FINAL ? HC : 1];
    int lane = threadIdx.x & 63;
    int wid = threadIdx.x >> 6;
    int d = blockIdx.x * 4 + wid;
    bool active = d < N;
    int start = 0, end = 0;
    if (active) { start = rowptr[d]; end = rowptr[d + 1]; }
    start = __builtin_amdgcn_readfirstlane(start);
    end = __builtin_amdgcn_readfirstlane(end);
    int h8 = lane & 7;
    int eslot = lane >> 3;
    float edh = active ? ed[d * 8 + h8] : 0.f;

    // ---- phase 1: per-head max over edges ----
    float mx = -3.0e38f;
    for (int q = start + eslot; q < end; q += 8) {
        int s = perm[q];
        float v = es[s * 8 + h8] + edh;
        v = (v >= 0.f) ? v : LEAKY * v;
        mx = fmaxf(mx, v);
    }
#pragma unroll
    for (int m = 8; m < 64; m <<= 1) mx = fmaxf(mx, __shfl_xor(mx, m));

    // head indices for this lane's feature elements
    int hh03 = FINAL ? (4 * lane) / C : (2 * lane) / C;
    int hh4 = FINAL ? (256 + lane) / C : 0;

    float acc[FINAL ? 5 : 2];
#pragma unroll
    for (int p = 0; p < (FINAL ? 5 : 2); p++) acc[p] = 0.f;

    // ---- fused phase 2+3 ----
    float dsum = 0.f;
    for (int q0 = start; q0 < end; q0 += 8) {
        int qq = q0 + eslot;
        int s_l = 0;
        float a_l = 0.f;
        if (qq < end) {
            s_l = perm[qq];
            float v = es[s_l * 8 + h8] + edh;
            v = (v >= 0.f) ? v : LEAKY * v;
            a_l = __expf(v - mx);
        }
        dsum += a_l;
#pragma unroll
        for (int e = 0; e < 8; e++) {
            if (q0 + e < end) {
                int s = __builtin_amdgcn_readlane(s_l, e * 8);
                const _Float16* hp = Hf + (size_t)s * HC;
                if constexpr (!FINAL) {
                    h2_t hv = *(const h2_t*)&hp[2 * lane];
                    float a0 = __shfl(a_l, e * 8 + hh03);
                    acc[0] = fmaf(a0, (float)hv[0], acc[0]);
                    acc[1] = fmaf(a0, (float)hv[1], acc[1]);
                } else {
                    h4_t hv = *(const h4_t*)&hp[4 * lane];
                    float hx = (float)hp[256 + lane];
                    float a03 = __shfl(a_l, e * 8 + hh03);
                    float a4 = __shfl(a_l, e * 8 + hh4);
                    acc[0] = fmaf(a03, (float)hv[0], acc[0]);
                    acc[1] = fmaf(a03, (float)hv[1], acc[1]);
                    acc[2] = fmaf(a03, (float)hv[2], acc[2]);
                    acc[3] = fmaf(a03, (float)hv[3], acc[3]);
                    acc[4] = fmaf(a4, hx, acc[4]);
                }
            }
        }
    }

    // ---- normalize ----
#pragma unroll
    for (int m = 8; m < 64; m <<= 1) dsum += __shfl_xor(dsum, m);
    float rden = 1.0f / (dsum + 1e-16f);

    if constexpr (!FINAL) {
        float r0 = __shfl(rden, hh03);
        acc[0] *= r0;
        acc[1] *= r0;
        if (active) {
            float2 bv = *(const float2*)&bias[2 * lane];
            float vx = acc[0] + bv.x;
            float vy = acc[1] + bv.y;
            vx = (vx > 0.f) ? vx : expm1f(vx);  // ELU
            vy = (vy > 0.f) ? vy : expm1f(vy);
            float* op = Out + (size_t)d * HC;
            *(float2*)&op[2 * lane] = make_float2(vx, vy);
        }
    } else {
        float r03 = __shfl(rden, hh03);
        float r4 = __shfl(rden, hh4);
#pragma unroll
        for (int j = 0; j < 4; j++) sfeat[wid][4 * lane + j] = acc[j] * r03;
        sfeat[wid][256 + lane] = acc[4] * r4;
        __syncthreads();
        if (active && lane < C) {
            float s = 0.f;
#pragma unroll
            for (int h = 0; h < 8; h++) s += sfeat[wid][h * C + lane];
            Out[(size_t)d * C + lane] = s * 0.125f + bias[lane];
        }
    }
}

// ---------------- launch ----------------

extern "C" void kernel_launch(void* const* d_in, const int* in_sizes, int n_in,
                              void* d_out, int out_size, void* d_ws, size_t ws_size,
                              hipStream_t stream) {
    const float* x   = (const float*)d_in[0];
    const int*   ei  = (const int*)d_in[1];
    const float* W1  = (const float*)d_in[2];
    const float* a1s = (const float*)d_in[3];
    const float* a1d = (const float*)d_in[4];
    const float* b1  = (const float*)d_in[5];
    const float* W2  = (const float*)d_in[6];
    const float* a2s = (const float*)d_in[7];
    const float* a2d = (const float*)d_in[8];
    const float* b2  = (const float*)d_in[9];
    const float* W3  = (const float*)d_in[10];
    const float* a3s = (const float*)d_in[11];
    const float* a3d = (const float*)d_in[12];
    const float* b3  = (const float*)d_in[13];
    float* out = (float*)d_out;

    const int N = in_sizes[0] / 128;
    const int E = in_sizes[1] / 2;
    const int ET = E + N;

    char* p = (char*)d_ws;
    _Float16* hbuf = (_Float16*)p; p += (size_t)N * 320 * 2;
    float* xbuf  = (float*)p; p += (size_t)N * 128 * 4;
    float* es    = (float*)p; p += (size_t)N * 8 * 4;
    float* edd   = (float*)p; p += (size_t)N * 8 * 4;
    int* cnt     = (int*)p;   p += (size_t)N * 4;
    int* rowptr  = (int*)p;   p += (size_t)(N + 1) * 4;
    int* perm    = (int*)p;   p += (size_t)ET * 4;

    // CSR build (shared by all 3 layers)
    hipMemsetAsync(cnt, 0, (size_t)N * 4, stream);
    count_kernel<<<(ET + 255) / 256, 256, 0, stream>>>(ei, cnt, E, ET);
    scan_kernel<<<1, 1024, 0, stream>>>(cnt, rowptr, N);
    hipMemsetAsync(cnt, 0, (size_t)N * 4, stream);
    scatter_kernel<<<(ET + 255) / 256, 256, 0, stream>>>(ei, rowptr, cnt, perm, E, ET);

    int agg_grid = (N + 3) / 4;
    int nh_grid = (N * 8 + 255) / 256;
    dim3 g128((N + 127) / 128, 2);   // HC=128
    dim3 g320((N + 127) / 128, 5);   // HC=320

    // layer 1: GAT(128 -> 8x16, concat) + ELU  (scores fused in GEMM, plain stores)
    gemm_kernel<16, true><<<g128, 256, 0, stream>>>(x, W1, a1s, a1d, hbuf, es, edd, N);
    agg_kernel<16, false><<<agg_grid, 256, 0, stream>>>(hbuf, es, edd, rowptr, perm, b1, xbuf, N);

    // layer 2: GAT(128 -> 8x16, concat) + ELU
    gemm_kernel<16, true><<<g128, 256, 0, stream>>>(xbuf, W2, a2s, a2d, hbuf, es, edd, N);
    agg_kernel<16, false><<<agg_grid, 256, 0, stream>>>(hbuf, es, edd, rowptr, perm, b2, xbuf, N);

    // layer 3: GAT(128 -> 8x40, mean over heads) — scores via separate fp16 pass
    gemm_kernel<40, false><<<g320, 256, 0, stream>>>(xbuf, W3, nullptr, nullptr, hbuf, nullptr, nullptr, N);
    attn_score_kernel<40><<<nh_grid, 256, 0, stream>>>(hbuf, a3s, a3d, es, edd, N);
    agg_kernel<40, true><<<agg_grid, 256, 0, stream>>>(hbuf, es, edd, rowptr, perm, b3, out, N);
}

// Round 6
// 483.113 us; speedup vs baseline: 1.4460x; 1.1750x over previous
//
#include <hip/hip_runtime.h>
#include <hip/hip_bf16.h>
#include <type_traits>

#define LEAKY 0.2f

using h2_t = __attribute__((ext_vector_type(2))) _Float16;
using h4_t = __attribute__((ext_vector_type(4))) _Float16;

// ---------------- CSR build ----------------

__global__ __launch_bounds__(256) void count_kernel(const int* __restrict__ ei,
                                                    int* __restrict__ cnt,
                                                    int E, int ET) {
    int e = blockIdx.x * 256 + threadIdx.x;
    if (e >= ET) return;
    int d = (e < E) ? ei[E + e] : (e - E);
    atomicAdd(&cnt[d], 1);
}

__global__ __launch_bounds__(1024) void scan_kernel(const int* __restrict__ cnt,
                                                    int* __restrict__ rowptr, int N) {
    __shared__ int sums[1024];
    int tid = threadIdx.x;
    int chunk = (N + 1023) >> 10;
    int begin = tid * chunk;
    int end = min(begin + chunk, N);
    int s = 0;
    for (int i = begin; i < end; i++) s += cnt[i];
    sums[tid] = s;
    __syncthreads();
    for (int off = 1; off < 1024; off <<= 1) {
        int v = 0;
        if (tid >= off) v = sums[tid - off];
        __syncthreads();
        sums[tid] += v;
        __syncthreads();
    }
    int base = (tid == 0) ? 0 : sums[tid - 1];
    for (int i = begin; i < end; i++) { rowptr[i] = base; base += cnt[i]; }
    if (tid == 0) rowptr[N] = sums[1023];
}

__global__ __launch_bounds__(256) void scatter_kernel(const int* __restrict__ ei,
                                                      const int* __restrict__ rowptr,
                                                      int* __restrict__ cursor,
                                                      int* __restrict__ perm,
                                                      int E, int ET) {
    int e = blockIdx.x * 256 + threadIdx.x;
    if (e >= ET) return;
    int s, d;
    if (e < E) { s = ei[e]; d = ei[E + e]; } else { s = e - E; d = s; }
    int pos = atomicAdd(&cursor[d], 1);
    perm[rowptr[d] + pos] = s;  // store src node id directly
}

// ---------------- GEMM (+ fused scores only for C=16, atomic-free) ----------------
// Hh[M,HC] = fp16(X[M,128] @ W[128,HC]).  A matrix (X) may be fp32 or fp16.
// FUSE=true (C=16): 64-col block = 4 whole heads -> shfl-reduce over 4 lanes,
// plain store of es/ed. No atomics anywhere.

#define XS_LD 132

template <int C, bool FUSE, typename AT>
__global__ __launch_bounds__(256) void gemm_kernel(const AT* __restrict__ X,
                                                   const float* __restrict__ W,
                                                   const float* __restrict__ As,
                                                   const float* __restrict__ Ad,
                                                   _Float16* __restrict__ Hh,
                                                   float* __restrict__ es,
                                                   float* __restrict__ ed,
                                                   int M) {
    constexpr int K = 128;
    constexpr int HC = 8 * C;
    __shared__ float Xs[32 * XS_LD];
    __shared__ float Ws[32 * 64];

    int tid = threadIdx.x;
    int tx = tid & 15;
    int ty = tid >> 4;
    int m0 = blockIdx.x * 128;
    int n0 = blockIdx.y * 64;

    float acc[8][4];
#pragma unroll
    for (int r = 0; r < 8; r++)
#pragma unroll
        for (int c = 0; c < 4; c++) acc[r][c] = 0.f;

    int lx_m = tid >> 3;
    int lx_kq = tid & 7;
    int lw_k = tid >> 4;
    int lw_nq = tid & 15;

    for (int k0 = 0; k0 < K; k0 += 32) {
#pragma unroll
        for (int p = 0; p < 4; p++) {
            int mi = p * 32 + lx_m;
            int row = m0 + mi;
            float vx = 0.f, vy = 0.f, vz = 0.f, vw = 0.f;
            if (row < M) {
                if constexpr (std::is_same_v<AT, float>) {
                    float4 v = *(const float4*)&X[(size_t)row * K + k0 + 4 * lx_kq];
                    vx = v.x; vy = v.y; vz = v.z; vw = v.w;
                } else {
                    h4_t v = *(const h4_t*)&X[(size_t)row * K + k0 + 4 * lx_kq];
                    vx = (float)v[0]; vy = (float)v[1]; vz = (float)v[2]; vw = (float)v[3];
                }
            }
            Xs[(4 * lx_kq + 0) * XS_LD + mi] = vx;
            Xs[(4 * lx_kq + 1) * XS_LD + mi] = vy;
            Xs[(4 * lx_kq + 2) * XS_LD + mi] = vz;
            Xs[(4 * lx_kq + 3) * XS_LD + mi] = vw;
        }
#pragma unroll
        for (int p = 0; p < 2; p++) {
            int kr = p * 16 + lw_k;
            float4 v = *(const float4*)&W[(size_t)(k0 + kr) * HC + n0 + 4 * lw_nq];
            *(float4*)&Ws[kr * 64 + 4 * lw_nq] = v;
        }
        __syncthreads();

#pragma unroll 8
        for (int kk = 0; kk < 32; kk++) {
            float4 a0 = *(float4*)&Xs[kk * XS_LD + ty * 8];
            float4 a1 = *(float4*)&Xs[kk * XS_LD + ty * 8 + 4];
            float4 bv = *(float4*)&Ws[kk * 64 + tx * 4];
            float av[8] = {a0.x, a0.y, a0.z, a0.w, a1.x, a1.y, a1.z, a1.w};
            float bw[4] = {bv.x, bv.y, bv.z, bv.w};
#pragma unroll
            for (int r = 0; r < 8; r++)
#pragma unroll
                for (int c = 0; c < 4; c++)
                    acc[r][c] = fmaf(av[r], bw[c], acc[r][c]);
        }
        __syncthreads();
    }

    int gcol0 = n0 + tx * 4;

#pragma unroll
    for (int r = 0; r < 8; r++) {
        int row = m0 + ty * 8 + r;
        bool ok = row < M;
        if (ok) {
            h4_t hv = {(_Float16)acc[r][0], (_Float16)acc[r][1],
                       (_Float16)acc[r][2], (_Float16)acc[r][3]};
            *(h4_t*)&Hh[(size_t)row * HC + gcol0] = hv;
        }
        if constexpr (FUSE) {
            int h = gcol0 / C;
            float4 av = *(const float4*)&As[gcol0];
            float4 dv = *(const float4*)&Ad[gcol0];
            float ps = acc[r][0] * av.x + acc[r][1] * av.y + acc[r][2] * av.z + acc[r][3] * av.w;
            float pd = acc[r][0] * dv.x + acc[r][1] * dv.y + acc[r][2] * dv.z + acc[r][3] * dv.w;
            ps += __shfl_xor(ps, 1); pd += __shfl_xor(pd, 1);
            ps += __shfl_xor(ps, 2); pd += __shfl_xor(pd, 2);
            if ((tx & 3) == 0 && ok) {
                es[row * 8 + h] = ps;
                ed[row * 8 + h] = pd;
            }
        }
    }
}

// ---------------- per-node attention scores (fp16 features) ----------------

template <int C>
__global__ __launch_bounds__(256) void attn_score_kernel(const _Float16* __restrict__ Hf,
                                                         const float* __restrict__ as_,
                                                         const float* __restrict__ ad_,
                                                         float* __restrict__ es,
                                                         float* __restrict__ ed, int N) {
    int i = blockIdx.x * 256 + threadIdx.x;
    if (i >= N * 8) return;
    int n = i >> 3, h = i & 7;
    const _Float16* hp = Hf + (size_t)n * 8 * C + h * C;
    const float* ap = as_ + h * C;
    const float* bp = ad_ + h * C;
    float s = 0.f, d = 0.f;
#pragma unroll
    for (int c = 0; c < C / 2; c++) {
        h2_t v = *(const h2_t*)&hp[2 * c];
        float v0 = (float)v[0], v1 = (float)v[1];
        s = fmaf(v0, ap[2 * c], s);
        d = fmaf(v0, bp[2 * c], d);
        s = fmaf(v1, ap[2 * c + 1], s);
        d = fmaf(v1, bp[2 * c + 1], d);
    }
    es[i] = s;
    ed[i] = d;
}

// ---------------- wave-per-dst softmax + aggregation (fp16 gather) ----------------
// 16-edge chunks. Per chunk: compute (src, unnorm-alpha) for 2 edge-slots in the
// 8-edge x 8-head lane layout; then BRANCHLESSLY stage all 16 feature gathers
// into register arrays (inactive edges read row 0 - harmless, alpha=0), then
// consume with shfl-broadcast alphas. This gives ~16-32 outstanding loads/wave
// (vs ~2 before) to hide L3 gather latency.
// OutT: _Float16 (mid layers, ELU) or float (final, head-mean).

template <int C, bool FINAL, typename OutT>
__global__ __launch_bounds__(256) void agg_kernel(const _Float16* __restrict__ Hf,
                                                  const float* __restrict__ es,
                                                  const float* __restrict__ ed,
                                                  const int* __restrict__ rowptr,
                                                  const int* __restrict__ perm,
                                                  const float* __restrict__ bias,
                                                  OutT* __restrict__ Out, int N) {
    constexpr int HC = 8 * C;
    __shared__ float sfeat[FINAL ? 4 : 1][FINAL ? HC : 1];
    int lane = threadIdx.x & 63;
    int wid = threadIdx.x >> 6;
    int d = blockIdx.x * 4 + wid;
    bool active = d < N;
    int start = 0, end = 0;
    if (active) { start = rowptr[d]; end = rowptr[d + 1]; }
    start = __builtin_amdgcn_readfirstlane(start);
    end = __builtin_amdgcn_readfirstlane(end);
    int h8 = lane & 7;
    int eslot = lane >> 3;
    float edh = active ? ed[d * 8 + h8] : 0.f;

    // ---- phase 1: per-head max over edges (2 slots/iter) ----
    float mx = -3.0e38f;
    for (int q = start + eslot; q < end; q += 16) {
        int s0 = perm[q];
        float v0 = es[s0 * 8 + h8] + edh;
        v0 = (v0 >= 0.f) ? v0 : LEAKY * v0;
        float v1 = -3.0e38f;
        if (q + 8 < end) {
            int s1 = perm[q + 8];
            v1 = es[s1 * 8 + h8] + edh;
            v1 = (v1 >= 0.f) ? v1 : LEAKY * v1;
        }
        mx = fmaxf(mx, fmaxf(v0, v1));
    }
#pragma unroll
    for (int m = 8; m < 64; m <<= 1) mx = fmaxf(mx, __shfl_xor(mx, m));

    // head indices for this lane's feature elements
    int hh03 = FINAL ? (4 * lane) / C : (2 * lane) / C;
    int hh4 = FINAL ? (256 + lane) / C : 0;

    float acc[FINAL ? 5 : 2];
#pragma unroll
    for (int p = 0; p < (FINAL ? 5 : 2); p++) acc[p] = 0.f;

    // ---- fused phase 2+3 over 16-edge chunks ----
    float dsum = 0.f;
    for (int q0 = start; q0 < end; q0 += 16) {
        // per-lane (src, alpha) for 2 edge slots
        int qq0 = q0 + eslot, qq1 = q0 + 8 + eslot;
        int s_l0 = 0, s_l1 = 0;
        float a_l0 = 0.f, a_l1 = 0.f;
        if (qq0 < end) {
            s_l0 = perm[qq0];
            float v = es[s_l0 * 8 + h8] + edh;
            v = (v >= 0.f) ? v : LEAKY * v;
            a_l0 = __expf(v - mx);
        }
        if (qq1 < end) {
            s_l1 = perm[qq1];
            float v = es[s_l1 * 8 + h8] + edh;
            v = (v >= 0.f) ? v : LEAKY * v;
            a_l1 = __expf(v - mx);
        }
        dsum += a_l0 + a_l1;

        // ---- stage all 16 gathers branchlessly ----
        if constexpr (!FINAL) {
            h2_t hv[16];
#pragma unroll
            for (int e = 0; e < 16; e++) {
                int s = (e < 8) ? __builtin_amdgcn_readlane(s_l0, e * 8)
                                : __builtin_amdgcn_readlane(s_l1, (e - 8) * 8);
                hv[e] = *(const h2_t*)&Hf[(size_t)s * HC + 2 * lane];
            }
#pragma unroll
            for (int e = 0; e < 16; e++) {
                float a0 = (e < 8) ? __shfl(a_l0, e * 8 + hh03)
                                   : __shfl(a_l1, (e - 8) * 8 + hh03);
                acc[0] = fmaf(a0, (float)hv[e][0], acc[0]);
                acc[1] = fmaf(a0, (float)hv[e][1], acc[1]);
            }
        } else {
            h4_t hv[16];
            _Float16 hx[16];
#pragma unroll
            for (int e = 0; e < 16; e++) {
                int s = (e < 8) ? __builtin_amdgcn_readlane(s_l0, e * 8)
                                : __builtin_amdgcn_readlane(s_l1, (e - 8) * 8);
                const _Float16* hp = Hf + (size_t)s * HC;
                hv[e] = *(const h4_t*)&hp[4 * lane];
                hx[e] = hp[256 + lane];
            }
#pragma unroll
            for (int e = 0; e < 16; e++) {
                float a03, a4;
                if (e < 8) {
                    a03 = __shfl(a_l0, e * 8 + hh03);
                    a4 = __shfl(a_l0, e * 8 + hh4);
                } else {
                    a03 = __shfl(a_l1, (e - 8) * 8 + hh03);
                    a4 = __shfl(a_l1, (e - 8) * 8 + hh4);
                }
                acc[0] = fmaf(a03, (float)hv[e][0], acc[0]);
                acc[1] = fmaf(a03, (float)hv[e][1], acc[1]);
                acc[2] = fmaf(a03, (float)hv[e][2], acc[2]);
                acc[3] = fmaf(a03, (float)hv[e][3], acc[3]);
                acc[4] = fmaf(a4, (float)hx[e], acc[4]);
            }
        }
    }

    // ---- normalize ----
#pragma unroll
    for (int m = 8; m < 64; m <<= 1) dsum += __shfl_xor(dsum, m);
    float rden = 1.0f / (dsum + 1e-16f);

    if constexpr (!FINAL) {
        float r0 = __shfl(rden, hh03);
        if (active) {
            float2 bv = *(const float2*)&bias[2 * lane];
            float vx = acc[0] * r0 + bv.x;
            float vy = acc[1] * r0 + bv.y;
            vx = (vx > 0.f) ? vx : expm1f(vx);  // ELU
            vy = (vy > 0.f) ? vy : expm1f(vy);
            h2_t o = {(_Float16)vx, (_Float16)vy};
            *(h2_t*)&Out[(size_t)d * HC + 2 * lane] = o;
        }
    } else {
        float r03 = __shfl(rden, hh03);
        float r4 = __shfl(rden, hh4);
#pragma unroll
        for (int j = 0; j < 4; j++) sfeat[wid][4 * lane + j] = acc[j] * r03;
        sfeat[wid][256 + lane] = acc[4] * r4;
        __syncthreads();
        if (active && lane < C) {
            float s = 0.f;
#pragma unroll
            for (int h = 0; h < 8; h++) s += sfeat[wid][h * C + lane];
            Out[(size_t)d * C + lane] = s * 0.125f + bias[lane];
        }
    }
}

// ---------------- launch ----------------

extern "C" void kernel_launch(void* const* d_in, const int* in_sizes, int n_in,
                              void* d_out, int out_size, void* d_ws, size_t ws_size,
                              hipStream_t stream) {
    const float* x   = (const float*)d_in[0];
    const int*   ei  = (const int*)d_in[1];
    const float* W1  = (const float*)d_in[2];
    const float* a1s = (const float*)d_in[3];
    const float* a1d = (const float*)d_in[4];
    const float* b1  = (const float*)d_in[5];
    const float* W2  = (const float*)d_in[6];
    const float* a2s = (const float*)d_in[7];
    const float* a2d = (const float*)d_in[8];
    const float* b2  = (const float*)d_in[9];
    const float* W3  = (const float*)d_in[10];
    const float* a3s = (const float*)d_in[11];
    const float* a3d = (const float*)d_in[12];
    const float* b3  = (const float*)d_in[13];
    float* out = (float*)d_out;

    const int N = in_sizes[0] / 128;
    const int E = in_sizes[1] / 2;
    const int ET = E + N;

    char* p = (char*)d_ws;
    _Float16* hbuf = (_Float16*)p; p += (size_t)N * 320 * 2;
    _Float16* xbuf = (_Float16*)p; p += (size_t)N * 128 * 2;
    float* es    = (float*)p; p += (size_t)N * 8 * 4;
    float* edd   = (float*)p; p += (size_t)N * 8 * 4;
    int* cnt     = (int*)p;   p += (size_t)N * 4;
    int* rowptr  = (int*)p;   p += (size_t)(N + 1) * 4;
    int* perm    = (int*)p;   p += (size_t)ET * 4;

    // CSR build (shared by all 3 layers)
    hipMemsetAsync(cnt, 0, (size_t)N * 4, stream);
    count_kernel<<<(ET + 255) / 256, 256, 0, stream>>>(ei, cnt, E, ET);
    scan_kernel<<<1, 1024, 0, stream>>>(cnt, rowptr, N);
    hipMemsetAsync(cnt, 0, (size_t)N * 4, stream);
    scatter_kernel<<<(ET + 255) / 256, 256, 0, stream>>>(ei, rowptr, cnt, perm, E, ET);

    int agg_grid = (N + 3) / 4;
    int nh_grid = (N * 8 + 255) / 256;
    dim3 g128((N + 127) / 128, 2);   // HC=128
    dim3 g320((N + 127) / 128, 5);   // HC=320

    // layer 1: GAT(128 -> 8x16, concat) + ELU  (scores fused in GEMM, fp32 A)
    gemm_kernel<16, true, float><<<g128, 256, 0, stream>>>(x, W1, a1s, a1d, hbuf, es, edd, N);
    agg_kernel<16, false, _Float16><<<agg_grid, 256, 0, stream>>>(hbuf, es, edd, rowptr, perm, b1, xbuf, N);

    // layer 2: GAT(128 -> 8x16, concat) + ELU  (fp16 A)
    gemm_kernel<16, true, _Float16><<<g128, 256, 0, stream>>>(xbuf, W2, a2s, a2d, hbuf, es, edd, N);
    agg_kernel<16, false, _Float16><<<agg_grid, 256, 0, stream>>>(hbuf, es, edd, rowptr, perm, b2, xbuf, N);

    // layer 3: GAT(128 -> 8x40, mean over heads) — scores via separate fp16 pass
    gemm_kernel<40, false, _Float16><<<g320, 256, 0, stream>>>(xbuf, W3, nullptr, nullptr, hbuf, nullptr, nullptr, N);
    attn_score_kernel<40><<<nh_grid, 256, 0, stream>>>(hbuf, a3s, a3d, es, edd, N);
    agg_kernel<40, true, float><<<agg_grid, 256, 0, stream>>>(hbuf, es, edd, rowptr, perm, b3, out, N);
}

// Round 7
// 408.084 us; speedup vs baseline: 1.7119x; 1.1839x over previous
//
#include <hip/hip_runtime.h>
#include <hip/hip_bf16.h>
#include <type_traits>

#define LEAKY 0.2f

using h2_t = __attribute__((ext_vector_type(2))) _Float16;
using h4_t = __attribute__((ext_vector_type(4))) _Float16;
using f16x8 = __attribute__((ext_vector_type(8))) _Float16;
using f32x4 = __attribute__((ext_vector_type(4))) float;

// ---------------- CSR build ----------------

__global__ __launch_bounds__(256) void count_kernel(const int* __restrict__ ei,
                                                    int* __restrict__ cnt,
                                                    int E, int ET) {
    int e = blockIdx.x * 256 + threadIdx.x;
    if (e >= ET) return;
    int d = (e < E) ? ei[E + e] : (e - E);
    atomicAdd(&cnt[d], 1);
}

__global__ __launch_bounds__(1024) void scan_kernel(const int* __restrict__ cnt,
                                                    int* __restrict__ rowptr, int N) {
    __shared__ int sums[1024];
    int tid = threadIdx.x;
    int chunk = (N + 1023) >> 10;
    int begin = tid * chunk;
    int end = min(begin + chunk, N);
    int s = 0;
    for (int i = begin; i < end; i++) s += cnt[i];
    sums[tid] = s;
    __syncthreads();
    for (int off = 1; off < 1024; off <<= 1) {
        int v = 0;
        if (tid >= off) v = sums[tid - off];
        __syncthreads();
        sums[tid] += v;
        __syncthreads();
    }
    int base = (tid == 0) ? 0 : sums[tid - 1];
    for (int i = begin; i < end; i++) { rowptr[i] = base; base += cnt[i]; }
    if (tid == 0) rowptr[N] = sums[1023];
}

__global__ __launch_bounds__(256) void scatter_kernel(const int* __restrict__ ei,
                                                      const int* __restrict__ rowptr,
                                                      int* __restrict__ cursor,
                                                      int* __restrict__ perm,
                                                      int E, int ET) {
    int e = blockIdx.x * 256 + threadIdx.x;
    if (e >= ET) return;
    int s, d;
    if (e < E) { s = ei[e]; d = ei[E + e]; } else { s = e - E; d = s; }
    int pos = atomicAdd(&cursor[d], 1);
    perm[rowptr[d] + pos] = s;  // store src node id directly
}

// ---------------- pre-pass conversions ----------------

__global__ __launch_bounds__(256) void cvt_x_kernel(const float* __restrict__ x,
                                                    _Float16* __restrict__ xh, int n4) {
    int i = blockIdx.x * 256 + threadIdx.x;
    if (i >= n4) return;
    float4 v = ((const float4*)x)[i];
    h4_t o = {(_Float16)v.x, (_Float16)v.y, (_Float16)v.z, (_Float16)v.w};
    ((h4_t*)xh)[i] = o;
}

// Wt[n][k] = fp16(W[k][n]);  W: [128, HC] fp32
__global__ __launch_bounds__(256) void wtrans_kernel(const float* __restrict__ W,
                                                     _Float16* __restrict__ Wt, int HC) {
    int i = blockIdx.x * 256 + threadIdx.x;
    if (i >= HC * 128) return;
    int n = i >> 7, k = i & 127;
    Wt[i] = (_Float16)W[k * HC + n];
}

// ---------------- MFMA GEMM: Hh[M,HC] = fp16(A[M,128] @ Wt^T) ----------------
// A fp16 [M,128]; Wt fp16 [HC,128]. Block tile 128x64, BK=64, 256 thr = 4 waves
// (2x2), wave tile 64x32 = 4x2 frags of v_mfma_f32_16x16x32_f16.
// LDS tiles XOR-swizzled (16B granule ^= row&7) -> conflict-free ds_read_b128.
// Epilogue: acc -> LDS fp16 [128][64] -> coalesced 16B stores; FUSE (C=16):
// es/ed computed from the LDS tile (head == 16-col group), no atomics.

template <int C, bool FUSE>
__global__ __launch_bounds__(256) void mgemm_kernel(const _Float16* __restrict__ A,
                                                    const _Float16* __restrict__ Wt,
                                                    const float* __restrict__ As_,
                                                    const float* __restrict__ Ad_,
                                                    _Float16* __restrict__ Hh,
                                                    float* __restrict__ es,
                                                    float* __restrict__ ed,
                                                    int M) {
    constexpr int K = 128;
    constexpr int HC = 8 * C;
    __shared__ __align__(16) unsigned char lds[128 * 128 + 64 * 128];  // 24 KB
    unsigned char* Asm = lds;                 // [128 rows][8 granules of 16B]
    unsigned char* Bsm = lds + 128 * 128;     // [64 cols][8 granules]

    int tid = threadIdx.x;
    int lane = tid & 63;
    int wid = tid >> 6;
    int wm = wid >> 1, wn = wid & 1;
    int m0 = blockIdx.x * 128, n0 = blockIdx.y * 64;

    f32x4 acc[4][2] = {};

    int fr = lane & 15;   // row/col within fragment
    int fk = lane >> 4;   // k-granule within 32-k chunk (0..3)

    for (int k0 = 0; k0 < K; k0 += 64) {
        // stage A: 1024 granules
#pragma unroll
        for (int p = 0; p < 4; p++) {
            int g = tid + p * 256;
            int row = g >> 3, kg = g & 7;
            uint4 v = {0, 0, 0, 0};
            int grow = m0 + row;
            if (grow < M) v = *(const uint4*)&A[(size_t)grow * K + k0 + kg * 8];
            *(uint4*)&Asm[row * 128 + ((kg ^ (row & 7)) << 4)] = v;
        }
        // stage B: 512 granules
#pragma unroll
        for (int p = 0; p < 2; p++) {
            int g = tid + p * 256;
            int col = g >> 3, kg = g & 7;
            uint4 v = *(const uint4*)&Wt[(size_t)(n0 + col) * K + k0 + kg * 8];
            *(uint4*)&Bsm[col * 128 + ((kg ^ (col & 7)) << 4)] = v;
        }
        __syncthreads();

#pragma unroll
        for (int kf = 0; kf < 2; kf++) {
            int kg = kf * 4 + fk;
            f16x8 af[4], bf[2];
#pragma unroll
            for (int mf = 0; mf < 4; mf++) {
                int row = wm * 64 + mf * 16 + fr;
                af[mf] = *(f16x8*)&Asm[row * 128 + ((kg ^ (row & 7)) << 4)];
            }
#pragma unroll
            for (int nf = 0; nf < 2; nf++) {
                int col = wn * 32 + nf * 16 + fr;
                bf[nf] = *(f16x8*)&Bsm[col * 128 + ((kg ^ (col & 7)) << 4)];
            }
#pragma unroll
            for (int mf = 0; mf < 4; mf++)
#pragma unroll
                for (int nf = 0; nf < 2; nf++)
                    acc[mf][nf] = __builtin_amdgcn_mfma_f32_16x16x32_f16(
                        af[mf], bf[nf], acc[mf][nf], 0, 0, 0);
        }
        __syncthreads();
    }

    // ---- epilogue: restage via LDS (fp16 [128][64]) ----
    _Float16* Es = (_Float16*)lds;
    int crow = wm * 64 + (lane >> 4) * 4;
    int ccol = wn * 32 + (lane & 15);
#pragma unroll
    for (int mf = 0; mf < 4; mf++)
#pragma unroll
        for (int nf = 0; nf < 2; nf++)
#pragma unroll
            for (int j = 0; j < 4; j++)
                Es[(crow + mf * 16 + j) * 64 + ccol + nf * 16] = (_Float16)acc[mf][nf][j];
    __syncthreads();

    // coalesced stores: 4 x 16B per thread
#pragma unroll
    for (int p = 0; p < 4; p++) {
        int g = tid + p * 256;
        int row = g >> 3, cg = g & 7;
        int grow = m0 + row;
        if (grow < M)
            *(uint4*)&Hh[(size_t)grow * HC + n0 + cg * 8] = *(uint4*)&Es[row * 64 + cg * 8];
    }

    if constexpr (FUSE) {
        // C==16: this 64-col block holds 4 whole heads
#pragma unroll
        for (int p = 0; p < 2; p++) {
            int t = tid + p * 256;
            int row = t >> 2, hq = t & 3;
            int grow = m0 + row;
            int h = (n0 >> 4) + hq;
            const _Float16* rp = &Es[row * 64 + hq * 16];
            const float* ap = &As_[h * 16];
            const float* dp = &Ad_[h * 16];
            float s = 0.f, d = 0.f;
#pragma unroll
            for (int c2 = 0; c2 < 16; c2++) {
                float v = (float)rp[c2];
                s = fmaf(v, ap[c2], s);
                d = fmaf(v, dp[c2], d);
            }
            if (grow < M) {
                es[grow * 8 + h] = s;
                ed[grow * 8 + h] = d;
            }
        }
    }
}

// ---------------- per-node attention scores (fp16 features) ----------------

template <int C>
__global__ __launch_bounds__(256) void attn_score_kernel(const _Float16* __restrict__ Hf,
                                                         const float* __restrict__ as_,
                                                         const float* __restrict__ ad_,
                                                         float* __restrict__ es,
                                                         float* __restrict__ ed, int N) {
    int i = blockIdx.x * 256 + threadIdx.x;
    if (i >= N * 8) return;
    int n = i >> 3, h = i & 7;
    const _Float16* hp = Hf + (size_t)n * 8 * C + h * C;
    const float* ap = as_ + h * C;
    const float* bp = ad_ + h * C;
    float s = 0.f, d = 0.f;
#pragma unroll
    for (int c = 0; c < C / 2; c++) {
        h2_t v = *(const h2_t*)&hp[2 * c];
        float v0 = (float)v[0], v1 = (float)v[1];
        s = fmaf(v0, ap[2 * c], s);
        d = fmaf(v0, bp[2 * c], d);
        s = fmaf(v1, ap[2 * c + 1], s);
        d = fmaf(v1, bp[2 * c + 1], d);
    }
    es[i] = s;
    ed[i] = d;
}

// ---------------- wave-per-dst softmax + aggregation (fp16 gather) ----------------
// 16-edge chunks, branchless staged gathers (see round-6 notes).

template <int C, bool FINAL, typename OutT>
__global__ __launch_bounds__(256) void agg_kernel(const _Float16* __restrict__ Hf,
                                                  const float* __restrict__ es,
                                                  const float* __restrict__ ed,
                                                  const int* __restrict__ rowptr,
                                                  const int* __restrict__ perm,
                                                  const float* __restrict__ bias,
                                                  OutT* __restrict__ Out, int N) {
    constexpr int HC = 8 * C;
    __shared__ float sfeat[FINAL ? 4 : 1][FINAL ? HC : 1];
    int lane = threadIdx.x & 63;
    int wid = threadIdx.x >> 6;
    int d = blockIdx.x * 4 + wid;
    bool active = d < N;
    int start = 0, end = 0;
    if (active) { start = rowptr[d]; end = rowptr[d + 1]; }
    start = __builtin_amdgcn_readfirstlane(start);
    end = __builtin_amdgcn_readfirstlane(end);
    int h8 = lane & 7;
    int eslot = lane >> 3;
    float edh = active ? ed[d * 8 + h8] : 0.f;

    // phase 1: per-head max
    float mx = -3.0e38f;
    for (int q = start + eslot; q < end; q += 16) {
        int s0 = perm[q];
        float v0 = es[s0 * 8 + h8] + edh;
        v0 = (v0 >= 0.f) ? v0 : LEAKY * v0;
        float v1 = -3.0e38f;
        if (q + 8 < end) {
            int s1 = perm[q + 8];
            v1 = es[s1 * 8 + h8] + edh;
            v1 = (v1 >= 0.f) ? v1 : LEAKY * v1;
        }
        mx = fmaxf(mx, fmaxf(v0, v1));
    }
#pragma unroll
    for (int m = 8; m < 64; m <<= 1) mx = fmaxf(mx, __shfl_xor(mx, m));

    int hh03 = FINAL ? (4 * lane) / C : (2 * lane) / C;
    int hh4 = FINAL ? (256 + lane) / C : 0;

    float acc[FINAL ? 5 : 2];
#pragma unroll
    for (int p = 0; p < (FINAL ? 5 : 2); p++) acc[p] = 0.f;

    float dsum = 0.f;
    for (int q0 = start; q0 < end; q0 += 16) {
        int qq0 = q0 + eslot, qq1 = q0 + 8 + eslot;
        int s_l0 = 0, s_l1 = 0;
        float a_l0 = 0.f, a_l1 = 0.f;
        if (qq0 < end) {
            s_l0 = perm[qq0];
            float v = es[s_l0 * 8 + h8] + edh;
            v = (v >= 0.f) ? v : LEAKY * v;
            a_l0 = __expf(v - mx);
        }
        if (qq1 < end) {
            s_l1 = perm[qq1];
            float v = es[s_l1 * 8 + h8] + edh;
            v = (v >= 0.f) ? v : LEAKY * v;
            a_l1 = __expf(v - mx);
        }
        dsum += a_l0 + a_l1;

        if constexpr (!FINAL) {
            h2_t hv[16];
#pragma unroll
            for (int e = 0; e < 16; e++) {
                int s = (e < 8) ? __builtin_amdgcn_readlane(s_l0, e * 8)
                                : __builtin_amdgcn_readlane(s_l1, (e - 8) * 8);
                hv[e] = *(const h2_t*)&Hf[(size_t)s * HC + 2 * lane];
            }
#pragma unroll
            for (int e = 0; e < 16; e++) {
                float a0 = (e < 8) ? __shfl(a_l0, e * 8 + hh03)
                                   : __shfl(a_l1, (e - 8) * 8 + hh03);
                acc[0] = fmaf(a0, (float)hv[e][0], acc[0]);
                acc[1] = fmaf(a0, (float)hv[e][1], acc[1]);
            }
        } else {
            h4_t hv[16];
            _Float16 hx[16];
#pragma unroll
            for (int e = 0; e < 16; e++) {
                int s = (e < 8) ? __builtin_amdgcn_readlane(s_l0, e * 8)
                                : __builtin_amdgcn_readlane(s_l1, (e - 8) * 8);
                const _Float16* hp = Hf + (size_t)s * HC;
                hv[e] = *(const h4_t*)&hp[4 * lane];
                hx[e] = hp[256 + lane];
            }
#pragma unroll
            for (int e = 0; e < 16; e++) {
                float a03, a4;
                if (e < 8) {
                    a03 = __shfl(a_l0, e * 8 + hh03);
                    a4 = __shfl(a_l0, e * 8 + hh4);
                } else {
                    a03 = __shfl(a_l1, (e - 8) * 8 + hh03);
                    a4 = __shfl(a_l1, (e - 8) * 8 + hh4);
                }
                acc[0] = fmaf(a03, (float)hv[e][0], acc[0]);
                acc[1] = fmaf(a03, (float)hv[e][1], acc[1]);
                acc[2] = fmaf(a03, (float)hv[e][2], acc[2]);
                acc[3] = fmaf(a03, (float)hv[e][3], acc[3]);
                acc[4] = fmaf(a4, (float)hx[e], acc[4]);
            }
        }
    }

#pragma unroll
    for (int m = 8; m < 64; m <<= 1) dsum += __shfl_xor(dsum, m);
    float rden = 1.0f / (dsum + 1e-16f);

    if constexpr (!FINAL) {
        float r0 = __shfl(rden, hh03);
        if (active) {
            float2 bv = *(const float2*)&bias[2 * lane];
            float vx = acc[0] * r0 + bv.x;
            float vy = acc[1] * r0 + bv.y;
            vx = (vx > 0.f) ? vx : expm1f(vx);  // ELU
            vy = (vy > 0.f) ? vy : expm1f(vy);
            h2_t o = {(_Float16)vx, (_Float16)vy};
            *(h2_t*)&Out[(size_t)d * HC + 2 * lane] = o;
        }
    } else {
        float r03 = __shfl(rden, hh03);
        float r4 = __shfl(rden, hh4);
#pragma unroll
        for (int j = 0; j < 4; j++) sfeat[wid][4 * lane + j] = acc[j] * r03;
        sfeat[wid][256 + lane] = acc[4] * r4;
        __syncthreads();
        if (active && lane < C) {
            float s = 0.f;
#pragma unroll
            for (int h = 0; h < 8; h++) s += sfeat[wid][h * C + lane];
            Out[(size_t)d * C + lane] = s * 0.125f + bias[lane];
        }
    }
}

// ---------------- launch ----------------

extern "C" void kernel_launch(void* const* d_in, const int* in_sizes, int n_in,
                              void* d_out, int out_size, void* d_ws, size_t ws_size,
                              hipStream_t stream) {
    const float* x   = (const float*)d_in[0];
    const int*   ei  = (const int*)d_in[1];
    const float* W1  = (const float*)d_in[2];
    const float* a1s = (const float*)d_in[3];
    const float* a1d = (const float*)d_in[4];
    const float* b1  = (const float*)d_in[5];
    const float* W2  = (const float*)d_in[6];
    const float* a2s = (const float*)d_in[7];
    const float* a2d = (const float*)d_in[8];
    const float* b2  = (const float*)d_in[9];
    const float* W3  = (const float*)d_in[10];
    const float* a3s = (const float*)d_in[11];
    const float* a3d = (const float*)d_in[12];
    const float* b3  = (const float*)d_in[13];
    float* out = (float*)d_out;

    const int N = in_sizes[0] / 128;
    const int E = in_sizes[1] / 2;
    const int ET = E + N;

    char* p = (char*)d_ws;
    _Float16* hbuf = (_Float16*)p; p += (size_t)N * 320 * 2;
    _Float16* xbuf = (_Float16*)p; p += (size_t)N * 128 * 2;
    float* es    = (float*)p; p += (size_t)N * 8 * 4;
    float* edd   = (float*)p; p += (size_t)N * 8 * 4;
    int* cnt     = (int*)p;   p += (size_t)N * 4;
    int* rowptr  = (int*)p;   p += (size_t)(N + 1) * 4;
    int* perm    = (int*)p;   p += (size_t)ET * 4;
    _Float16* Wt1 = (_Float16*)p; p += 128 * 128 * 2;
    _Float16* Wt2 = (_Float16*)p; p += 128 * 128 * 2;
    _Float16* Wt3 = (_Float16*)p; p += 320 * 128 * 2;

    // CSR build (shared by all 3 layers)
    hipMemsetAsync(cnt, 0, (size_t)N * 4, stream);
    count_kernel<<<(ET + 255) / 256, 256, 0, stream>>>(ei, cnt, E, ET);
    scan_kernel<<<1, 1024, 0, stream>>>(cnt, rowptr, N);
    hipMemsetAsync(cnt, 0, (size_t)N * 4, stream);
    scatter_kernel<<<(ET + 255) / 256, 256, 0, stream>>>(ei, rowptr, cnt, perm, E, ET);

    // pre-pass conversions
    cvt_x_kernel<<<(N * 32 + 255) / 256, 256, 0, stream>>>(x, xbuf, N * 32);
    wtrans_kernel<<<(128 * 128 + 255) / 256, 256, 0, stream>>>(W1, Wt1, 128);
    wtrans_kernel<<<(128 * 128 + 255) / 256, 256, 0, stream>>>(W2, Wt2, 128);
    wtrans_kernel<<<(320 * 128 + 255) / 256, 256, 0, stream>>>(W3, Wt3, 320);

    int agg_grid = (N + 3) / 4;
    int nh_grid = (N * 8 + 255) / 256;
    int gx = (N + 127) / 128;
    dim3 g128(gx, 2);   // HC=128
    dim3 g320(gx, 5);   // HC=320

    // layer 1: GAT(128 -> 8x16, concat) + ELU  (scores fused, MFMA)
    mgemm_kernel<16, true><<<g128, 256, 0, stream>>>(xbuf, Wt1, a1s, a1d, hbuf, es, edd, N);
    agg_kernel<16, false, _Float16><<<agg_grid, 256, 0, stream>>>(hbuf, es, edd, rowptr, perm, b1, xbuf, N);

    // layer 2: GAT(128 -> 8x16, concat) + ELU
    mgemm_kernel<16, true><<<g128, 256, 0, stream>>>(xbuf, Wt2, a2s, a2d, hbuf, es, edd, N);
    agg_kernel<16, false, _Float16><<<agg_grid, 256, 0, stream>>>(hbuf, es, edd, rowptr, perm, b2, xbuf, N);

    // layer 3: GAT(128 -> 8x40, mean over heads)
    mgemm_kernel<40, false><<<g320, 256, 0, stream>>>(xbuf, Wt3, nullptr, nullptr, hbuf, nullptr, nullptr, N);
    attn_score_kernel<40><<<nh_grid, 256, 0, stream>>>(hbuf, a3s, a3d, es, edd, N);
    agg_kernel<40, true, float><<<agg_grid, 256, 0, stream>>>(hbuf, es, edd, rowptr, perm, b3, out, N);
}